// Round 1
// baseline (404.181 us; speedup 1.0000x reference)
//
#include <hip/hip_runtime.h>
#include <hip/hip_bf16.h>

typedef unsigned short u16;
using short8 = __attribute__((ext_vector_type(8))) short;
using f32x4  = __attribute__((ext_vector_type(4))) float;

#define T_SEQ 2048
#define C_DIM 1024
#define NH 16
#define HD 64
#define BH 64   // B*NH

__device__ __forceinline__ u16 f2bf(float f) {
    unsigned int u = __float_as_uint(f);
    unsigned int r = (u + 0x7fffu + ((u >> 16) & 1u)) >> 16;
    return (u16)r;
}

// ---------------- fp32 -> bf16 convert, 8 elems/thread ----------------
__global__ __launch_bounds__(256) void cvt_f32_bf16(const float* __restrict__ in,
                                                    u16* __restrict__ out, int n8) {
    int i = blockIdx.x * blockDim.x + threadIdx.x;
    if (i >= n8) return;
    const float4* p = (const float4*)in + (size_t)i * 2;
    float4 a = p[0], b = p[1];
    short8 o;
    o[0] = (short)f2bf(a.x); o[1] = (short)f2bf(a.y);
    o[2] = (short)f2bf(a.z); o[3] = (short)f2bf(a.w);
    o[4] = (short)f2bf(b.x); o[5] = (short)f2bf(b.y);
    o[6] = (short)f2bf(b.z); o[7] = (short)f2bf(b.w);
    *(short8*)(out + (size_t)i * 8) = o;
}

// ---------------- bf16 GEMM: C[M][N] = A[M][K] * Bt[N][K]^T + bias ----------------
// 128x128 tile, BK=32, 256 threads (4 waves, 2x2 of 64x64), 16x16x32 MFMA.
// EPI=0: scatter to Q/K/V bf16 [BH][T][D] with bias. EPI=1: fp32 C with bias.
template <int EPI>
__global__ __launch_bounds__(256) void gemm_bt(const u16* __restrict__ A,
                                               const u16* __restrict__ Bt,
                                               const float* __restrict__ bias,
                                               u16* __restrict__ qb, u16* __restrict__ kb,
                                               u16* __restrict__ vb, float* __restrict__ Cf,
                                               int M, int N, int K) {
    __shared__ __align__(16) u16 Al[128][40];
    __shared__ __align__(16) u16 Bl[128][40];
    const int tid = threadIdx.x;
    const int lane = tid & 63, wid = tid >> 6;
    const int li = lane & 15, g = lane >> 4;
    const int wr = (wid >> 1) * 64, wc = (wid & 1) * 64;
    const size_t m0 = (size_t)blockIdx.y * 128, n0 = (size_t)blockIdx.x * 128;
    const int srow = tid >> 1, sseg = tid & 1;

    f32x4 acc[4][4] = {};

    for (int k0 = 0; k0 < K; k0 += 32) {
        const u16* asrc = A + (m0 + srow) * (size_t)K + k0 + sseg * 16;
        const u16* bsrc = Bt + (n0 + srow) * (size_t)K + k0 + sseg * 16;
        short8 a0 = *(const short8*)asrc;
        short8 a1 = *(const short8*)(asrc + 8);
        short8 b0 = *(const short8*)bsrc;
        short8 b1 = *(const short8*)(bsrc + 8);
        *(short8*)&Al[srow][sseg * 16]     = a0;
        *(short8*)&Al[srow][sseg * 16 + 8] = a1;
        *(short8*)&Bl[srow][sseg * 16]     = b0;
        *(short8*)&Bl[srow][sseg * 16 + 8] = b1;
        __syncthreads();
        short8 af[4], bf[4];
#pragma unroll
        for (int i = 0; i < 4; i++) af[i] = *(const short8*)&Al[wr + i * 16 + li][g * 8];
#pragma unroll
        for (int i = 0; i < 4; i++) bf[i] = *(const short8*)&Bl[wc + i * 16 + li][g * 8];
#pragma unroll
        for (int mi = 0; mi < 4; mi++)
#pragma unroll
            for (int ni = 0; ni < 4; ni++)
                acc[mi][ni] = __builtin_amdgcn_mfma_f32_16x16x32_bf16(af[mi], bf[ni],
                                                                      acc[mi][ni], 0, 0, 0);
        __syncthreads();
    }

#pragma unroll
    for (int mi = 0; mi < 4; mi++)
#pragma unroll
        for (int ni = 0; ni < 4; ni++)
#pragma unroll
            for (int r = 0; r < 4; r++) {
                size_t row = m0 + wr + mi * 16 + g * 4 + r;
                size_t col = n0 + wc + ni * 16 + li;
                float val = acc[mi][ni][r] + bias[col];
                if (EPI == 0) {
                    int which = (int)(col >> 10);
                    int rem = (int)(col & 1023);
                    int h = rem >> 6, d = rem & 63;
                    size_t b = row >> 11, t = row & 2047;
                    u16* dst = (which == 0) ? qb : (which == 1) ? kb : vb;
                    dst[(((b * NH) + h) * T_SEQ + t) * HD + d] = f2bf(val);
                } else {
                    Cf[row * (size_t)N + col] = val;
                }
            }
}

// ---------------- causal flash attention ----------------
// grid (T/64, BH), 256 threads = 4 waves; wave w owns q-rows [q0+16w, q0+16w+16)
__global__ __launch_bounds__(256) void attn_fwd(const u16* __restrict__ Q,
                                                const u16* __restrict__ K,
                                                const u16* __restrict__ V,
                                                u16* __restrict__ O) {
    __shared__ __align__(16) u16 Kl[64][72];
    __shared__ __align__(16) u16 Vt[64][72];   // transposed: Vt[d][kv]
    __shared__ __align__(16) u16 Pl[4][16][72];
    const int tid = threadIdx.x;
    const int lane = tid & 63, wid = tid >> 6;
    const int li = lane & 15, g = lane >> 4;
    const int qt = blockIdx.x, bh = blockIdx.y;
    const int q0 = qt * 64;
    const size_t base_bh = (size_t)bh * T_SEQ;

    short8 qf[2];
    {
        size_t qrow = base_bh + q0 + wid * 16 + li;
        qf[0] = *(const short8*)(Q + qrow * HD + g * 8);
        qf[1] = *(const short8*)(Q + qrow * HD + 32 + g * 8);
    }

    f32x4 o[4] = {};
    float m_run[4], l_run[4];
#pragma unroll
    for (int r = 0; r < 4; r++) { m_run[r] = -1e30f; l_run[r] = 0.f; }

    const int srow = tid >> 2, sseg = tid & 3;
    const int nkt = qt + 1;

    for (int kt = 0; kt < nkt; kt++) {
        const int kv0 = kt * 64;
        {
            const u16* ksrc = K + (base_bh + kv0 + srow) * HD + sseg * 16;
            short8 k0v = *(const short8*)ksrc;
            short8 k1v = *(const short8*)(ksrc + 8);
            *(short8*)&Kl[srow][sseg * 16]     = k0v;
            *(short8*)&Kl[srow][sseg * 16 + 8] = k1v;
            const u16* vsrc = V + (base_bh + kv0 + srow) * HD + sseg * 16;
            short8 v0 = *(const short8*)vsrc;
            short8 v1 = *(const short8*)(vsrc + 8);
#pragma unroll
            for (int j = 0; j < 8; j++) Vt[sseg * 16 + j][srow] = (u16)v0[j];
#pragma unroll
            for (int j = 0; j < 8; j++) Vt[sseg * 16 + 8 + j][srow] = (u16)v1[j];
        }
        __syncthreads();

        // S = Q K^T  (per wave: 16 q-rows x 64 kv-cols)
        f32x4 s[4];
#pragma unroll
        for (int nt = 0; nt < 4; nt++) {
            f32x4 a = {};
#pragma unroll
            for (int kk = 0; kk < 2; kk++) {
                short8 kbf = *(const short8*)&Kl[nt * 16 + li][kk * 32 + g * 8];
                a = __builtin_amdgcn_mfma_f32_16x16x32_bf16(qf[kk], kbf, a, 0, 0, 0);
            }
            s[nt] = a;
        }

        // scale + causal mask + online softmax (fp32)
        float pm[4], rs[4];
#pragma unroll
        for (int r = 0; r < 4; r++) {
            int rowg = q0 + wid * 16 + g * 4 + r;
            float mx = -1e30f;
#pragma unroll
            for (int nt = 0; nt < 4; nt++) {
                int colg = kv0 + nt * 16 + li;
                float sv = s[nt][r] * 0.125f;
                if (colg > rowg) sv = -1e9f;
                s[nt][r] = sv;
                mx = fmaxf(mx, sv);
            }
            pm[r] = mx;
        }
#pragma unroll
        for (int off = 1; off < 16; off <<= 1)
#pragma unroll
            for (int r = 0; r < 4; r++) pm[r] = fmaxf(pm[r], __shfl_xor(pm[r], off));
#pragma unroll
        for (int r = 0; r < 4; r++) {
            float mnew = fmaxf(m_run[r], pm[r]);
            float alpha = __expf(m_run[r] - mnew);
            m_run[r] = mnew;
            l_run[r] *= alpha;
#pragma unroll
            for (int nt = 0; nt < 4; nt++) o[nt][r] *= alpha;
            float sum = 0.f;
#pragma unroll
            for (int nt = 0; nt < 4; nt++) {
                float p = __expf(s[nt][r] - mnew);
                s[nt][r] = p;
                sum += p;
            }
            rs[r] = sum;
        }
#pragma unroll
        for (int off = 1; off < 16; off <<= 1)
#pragma unroll
            for (int r = 0; r < 4; r++) rs[r] += __shfl_xor(rs[r], off);
#pragma unroll
        for (int r = 0; r < 4; r++) l_run[r] += rs[r];

        // P -> LDS (bf16), re-read in A-fragment layout
#pragma unroll
        for (int nt = 0; nt < 4; nt++)
#pragma unroll
            for (int r = 0; r < 4; r++)
                Pl[wid][g * 4 + r][nt * 16 + li] = f2bf(s[nt][r]);

#pragma unroll
        for (int ks = 0; ks < 2; ks++) {
            short8 pa = *(const short8*)&Pl[wid][li][ks * 32 + g * 8];
#pragma unroll
            for (int nt = 0; nt < 4; nt++) {
                short8 vbf = *(const short8*)&Vt[nt * 16 + li][ks * 32 + g * 8];
                o[nt] = __builtin_amdgcn_mfma_f32_16x16x32_bf16(pa, vbf, o[nt], 0, 0, 0);
            }
        }
        __syncthreads();
    }

    const int bq = bh >> 4, h = bh & 15;
#pragma unroll
    for (int r = 0; r < 4; r++) {
        int trow = q0 + wid * 16 + g * 4 + r;
        float inv = 1.0f / l_run[r];
#pragma unroll
        for (int nt = 0; nt < 4; nt++)
            O[((size_t)bq * T_SEQ + trow) * C_DIM + h * HD + nt * 16 + li] =
                f2bf(o[nt][r] * inv);
    }
}

extern "C" void kernel_launch(void* const* d_in, const int* in_sizes, int n_in,
                              void* d_out, int out_size, void* d_ws, size_t ws_size,
                              hipStream_t stream) {
    const float* x     = (const float*)d_in[0];
    // d_in[1] = mask (causal, known analytically — unused)
    const float* W_qkv = (const float*)d_in[2];
    const float* b_qkv = (const float*)d_in[3];
    const float* W_out = (const float*)d_in[4];
    const float* b_out = (const float*)d_in[5];
    float* out = (float*)d_out;

    char* w = (char*)d_ws;
    u16* xb    = (u16*)(w);                 // 16,777,216 B (reused as attn out)
    u16* wqkvb = (u16*)(w + 16777216);      //  6,291,456 B
    u16* woutb = (u16*)(w + 23068672);      //  2,097,152 B
    u16* qb    = (u16*)(w + 25165824);      // 16,777,216 B
    u16* kb    = (u16*)(w + 41943040);      // 16,777,216 B
    u16* vb    = (u16*)(w + 58720256);      // 16,777,216 B
    u16* attnb = xb;                        // x is dead after QKV GEMM

    // converts
    cvt_f32_bf16<<<4096, 256, 0, stream>>>(x, xb, 1048576);       // 8,388,608 elems
    cvt_f32_bf16<<<1536, 256, 0, stream>>>(W_qkv, wqkvb, 393216); // 3,145,728
    cvt_f32_bf16<<<512, 256, 0, stream>>>(W_out, woutb, 131072);  // 1,048,576

    // QKV projection: [8192x1024] x [3072x1024]^T -> scatter Q/K/V
    gemm_bt<0><<<dim3(24, 64), 256, 0, stream>>>(xb, wqkvb, b_qkv, qb, kb, vb, nullptr,
                                                 8192, 3072, 1024);

    // causal attention
    attn_fwd<<<dim3(32, 64), 256, 0, stream>>>(qb, kb, vb, attnb);

    // output projection: [8192x1024] x [1024x1024]^T -> fp32 out
    gemm_bt<1><<<dim3(8, 64), 256, 0, stream>>>(attnb, woutb, b_out, nullptr, nullptr,
                                                nullptr, out, 8192, 1024, 1024);
}

// Round 2
// 274.903 us; speedup vs baseline: 1.4703x; 1.4703x over previous
//
#include <hip/hip_runtime.h>
#include <hip/hip_bf16.h>

typedef unsigned short u16;
typedef unsigned int u32;
using short8 = __attribute__((ext_vector_type(8))) short;
using f32x4  = __attribute__((ext_vector_type(4))) float;
using f32x16 = __attribute__((ext_vector_type(16))) float;
using uint2v = __attribute__((ext_vector_type(2))) u32;

#define T_SEQ 2048
#define C_DIM 1024
#define NH 16
#define HD 64

__device__ __forceinline__ u16 f2bf(float f) {
    unsigned int u = __float_as_uint(f);
    unsigned int r = (u + 0x7fffu + ((u >> 16) & 1u)) >> 16;
    return (u16)r;
}
__device__ __forceinline__ u32 pk2(float lo, float hi) {
    return ((u32)f2bf(hi) << 16) | (u32)f2bf(lo);
}
__device__ __forceinline__ short8 mk8(u32 a, u32 b, u32 c, u32 d) {
    union { u32 u[4]; short8 s; } t;
    t.u[0] = a; t.u[1] = b; t.u[2] = c; t.u[3] = d;
    return t.s;
}
// global -> LDS direct DMA, 16B per lane; LDS dest = wave-uniform base + lane*16
__device__ __forceinline__ void gl_lds16(const u16* g, u16* l) {
    __builtin_amdgcn_global_load_lds(
        (const __attribute__((address_space(1))) unsigned int*)g,
        (__attribute__((address_space(3))) unsigned int*)l, 16, 0, 0);
}

// ---------------- fp32 -> bf16 convert, 8 elems/thread ----------------
__global__ __launch_bounds__(256) void cvt_f32_bf16(const float* __restrict__ in,
                                                    u16* __restrict__ out, int n8) {
    int i = blockIdx.x * blockDim.x + threadIdx.x;
    if (i >= n8) return;
    const float4* p = (const float4*)in + (size_t)i * 2;
    float4 a = p[0], b = p[1];
    short8 o;
    o[0] = (short)f2bf(a.x); o[1] = (short)f2bf(a.y);
    o[2] = (short)f2bf(a.z); o[3] = (short)f2bf(a.w);
    o[4] = (short)f2bf(b.x); o[5] = (short)f2bf(b.y);
    o[6] = (short)f2bf(b.z); o[7] = (short)f2bf(b.w);
    *(short8*)(out + (size_t)i * 8) = o;
}

// ---------------- bf16 GEMM: C[M][N] = A[M][K] * Bt[N][K]^T + bias ----------------
// EPI=0: scatter to Q/K/V bf16 [BH][T][D] with bias (Q pre-scaled by 1/8).
// EPI=1: fp32 C with bias.
template <int EPI>
__global__ __launch_bounds__(256) void gemm_bt(const u16* __restrict__ A,
                                               const u16* __restrict__ Bt,
                                               const float* __restrict__ bias,
                                               u16* __restrict__ qb, u16* __restrict__ kb,
                                               u16* __restrict__ vb, float* __restrict__ Cf,
                                               int M, int N, int K) {
    __shared__ __align__(16) u16 Al[128][40];
    __shared__ __align__(16) u16 Bl[128][40];
    const int tid = threadIdx.x;
    const int lane = tid & 63, wid = tid >> 6;
    const int li = lane & 15, g = lane >> 4;
    const int wr = (wid >> 1) * 64, wc = (wid & 1) * 64;
    const size_t m0 = (size_t)blockIdx.y * 128, n0 = (size_t)blockIdx.x * 128;
    const int srow = tid >> 1, sseg = tid & 1;

    f32x4 acc[4][4] = {};

    for (int k0 = 0; k0 < K; k0 += 32) {
        const u16* asrc = A + (m0 + srow) * (size_t)K + k0 + sseg * 16;
        const u16* bsrc = Bt + (n0 + srow) * (size_t)K + k0 + sseg * 16;
        short8 a0 = *(const short8*)asrc;
        short8 a1 = *(const short8*)(asrc + 8);
        short8 b0 = *(const short8*)bsrc;
        short8 b1 = *(const short8*)(bsrc + 8);
        *(short8*)&Al[srow][sseg * 16]     = a0;
        *(short8*)&Al[srow][sseg * 16 + 8] = a1;
        *(short8*)&Bl[srow][sseg * 16]     = b0;
        *(short8*)&Bl[srow][sseg * 16 + 8] = b1;
        __syncthreads();
        short8 af[4], bf[4];
#pragma unroll
        for (int i = 0; i < 4; i++) af[i] = *(const short8*)&Al[wr + i * 16 + li][g * 8];
#pragma unroll
        for (int i = 0; i < 4; i++) bf[i] = *(const short8*)&Bl[wc + i * 16 + li][g * 8];
#pragma unroll
        for (int mi = 0; mi < 4; mi++)
#pragma unroll
            for (int ni = 0; ni < 4; ni++)
                acc[mi][ni] = __builtin_amdgcn_mfma_f32_16x16x32_bf16(af[mi], bf[ni],
                                                                      acc[mi][ni], 0, 0, 0);
        __syncthreads();
    }

#pragma unroll
    for (int mi = 0; mi < 4; mi++)
#pragma unroll
        for (int ni = 0; ni < 4; ni++)
#pragma unroll
            for (int r = 0; r < 4; r++) {
                size_t row = m0 + wr + mi * 16 + g * 4 + r;
                size_t col = n0 + wc + ni * 16 + li;
                float val = acc[mi][ni][r] + bias[col];
                if (EPI == 0) {
                    int which = (int)(col >> 10);
                    int rem = (int)(col & 1023);
                    int h = rem >> 6, d = rem & 63;
                    size_t b = row >> 11, t = row & 2047;
                    if (which == 0) val *= 0.125f;   // fold 1/sqrt(D) into Q
                    u16* dst = (which == 0) ? qb : (which == 1) ? kb : vb;
                    dst[(((b * NH) + h) * T_SEQ + t) * HD + d] = f2bf(val);
                } else {
                    Cf[row * (size_t)N + col] = val;
                }
            }
}

// ---------------- V transpose: [bh][t][d] -> [bh][d][t] ----------------
__global__ __launch_bounds__(256) void vtrans(const u16* __restrict__ V,
                                              u16* __restrict__ Vt) {
    __shared__ u16 L[128][72];
    const int tid = threadIdx.x;
    const int bh = blockIdx.y;
    const int t0 = blockIdx.x * 128;
    {
        int r = tid >> 1, cb = (tid & 1) * 32;
        const u16* src = V + ((size_t)bh * T_SEQ + t0 + r) * HD + cb;
#pragma unroll
        for (int j = 0; j < 4; j++)
            *(short8*)&L[r][cb + j * 8] = *(const short8*)(src + j * 8);
    }
    __syncthreads();
    {
        int d = tid >> 2, ts = (tid & 3) * 32;
        u16* dst = Vt + ((size_t)bh * HD + d) * T_SEQ + t0 + ts;
#pragma unroll
        for (int c = 0; c < 4; c++) {
            short8 o;
#pragma unroll
            for (int j = 0; j < 8; j++) o[j] = (short)L[ts + c * 8 + j][d];
            *(short8*)(dst + c * 8) = o;
        }
    }
}

// ---------------- causal flash attention, swapped-QK 32x32 MFMA ----------------
// grid 1024 = (16 qtiles x 64 bh), XCD-chunked; 256 thr = 4 waves x 32 q-rows.
// K/Vt staged via global_load_lds with pre-swizzled source (chunk ^= row&7),
// double-buffered, 1 barrier/tile, next-tile loads in flight during compute.
__global__ __launch_bounds__(256) void attn_fwd2(const u16* __restrict__ Q,
                                                 const u16* __restrict__ K,
                                                 const u16* __restrict__ Vt,
                                                 u16* __restrict__ O) {
    __shared__ __align__(16) u16 KL[2][64 * 64];
    __shared__ __align__(16) u16 VL[2][64 * 64];
    const int tid = threadIdx.x;
    const int lane = tid & 63, wid = tid >> 6;
    const int l31 = lane & 31, hi = lane >> 5;

    const int wg = blockIdx.x;
    const int xcd = wg & 7, slot = wg >> 3;
    const int bh = (xcd << 3) + (slot >> 4);     // 8 bh per XCD -> K/V L2-resident
    const int qt = 15 - (slot & 15);             // big blocks dispatched first
    const int q0 = qt * 128;
    const size_t bhT = (size_t)bh * T_SEQ;
    const int qw0 = q0 + wid * 32;

    // Q fragments in registers (Q pre-scaled by 1/8 in the QKV GEMM)
    short8 qf[4];
    {
        const u16* qp = Q + (bhT + qw0 + l31) * HD + hi * 8;
#pragma unroll
        for (int s = 0; s < 4; s++) qf[s] = *(const short8*)(qp + s * 16);
    }

    f32x16 o0 = {}, o1 = {};
    float m_run = -3e38f, l_run = 0.f;

    const int srow = lane >> 3;     // 0..7 within 8-row group
    const int sch = lane & 7;       // 16B chunk slot
    const int nkt = 2 * qt + 2;

    // prologue: stage tile 0 into buffer 0
#pragma unroll
    for (int i = 0; i < 2; i++) {
        int row = wid * 16 + i * 8 + srow;
        int ch = sch ^ (row & 7);
        gl_lds16(K + (bhT + row) * HD + ch * 8, &KL[0][(wid * 16 + i * 8) * 64]);
        gl_lds16(Vt + ((size_t)bh * HD + row) * T_SEQ + ch * 8,
                 &VL[0][(wid * 16 + i * 8) * 64]);
    }

    for (int kt = 0; kt < nkt; kt++) {
        __syncthreads();   // drains vmcnt: tile kt resident; prev compute done
        if (kt + 1 < nkt) {
            const int kv0n = (kt + 1) * 64;
            const int nb = (kt + 1) & 1;
#pragma unroll
            for (int i = 0; i < 2; i++) {
                int row = wid * 16 + i * 8 + srow;
                int ch = sch ^ (row & 7);
                gl_lds16(K + (bhT + kv0n + row) * HD + ch * 8,
                         &KL[nb][(wid * 16 + i * 8) * 64]);
                gl_lds16(Vt + ((size_t)bh * HD + row) * T_SEQ + kv0n + ch * 8,
                         &VL[nb][(wid * 16 + i * 8) * 64]);
            }
        }
        const int kv0 = kt * 64;
        if (kv0 > qw0) continue;     // wave-uniform; barriers stay at loop top
        const u16* KLb = KL[kt & 1];
        const u16* VLb = VL[kt & 1];
        const int x7 = l31 & 7;

        // S^T[kv][q] = K . Q^T  (two kv-halves of 32)
        f32x16 s0 = {}, s1 = {};
#pragma unroll
        for (int sl = 0; sl < 4; sl++) {
            int ch = ((sl * 2 + hi) ^ x7) * 8;
            short8 ka = *(const short8*)&KLb[l31 * 64 + ch];
            s0 = __builtin_amdgcn_mfma_f32_32x32x16_bf16(ka, qf[sl], s0, 0, 0, 0);
            short8 kb2 = *(const short8*)&KLb[(32 + l31) * 64 + ch];
            s1 = __builtin_amdgcn_mfma_f32_32x32x16_bf16(kb2, qf[sl], s1, 0, 0, 0);
        }

        const int qg = qw0 + l31;
        if (kv0 + 63 > qw0) {       // boundary tile: causal mask
#pragma unroll
            for (int r = 0; r < 16; r++) {
                int kvr = kv0 + (r & 3) + 8 * (r >> 2) + 4 * hi;
                if (kvr > qg) s0[r] = -1e30f;
                if (kvr + 32 > qg) s1[r] = -1e30f;
            }
        }

        // per-q max (lane-local over 32 regs + partner exchange)
        float pm = -3e38f;
#pragma unroll
        for (int r = 0; r < 16; r++) pm = fmaxf(pm, fmaxf(s0[r], s1[r]));
        pm = fmaxf(pm, __shfl_xor(pm, 32));

        // defer-max: rescale only if some q grew by > 8
        if (!__all(pm <= m_run + 8.0f)) {
            float mnew = fmaxf(m_run, pm);
            float alpha = __expf(m_run - mnew);
            l_run *= alpha;
            m_run = mnew;
#pragma unroll
            for (int r = 0; r < 16; r++) {
                int qr = (r & 3) + 8 * (r >> 2) + 4 * hi;
                float ar = __shfl(alpha, qr);
                o0[r] *= ar;
                o1[r] *= ar;
            }
        }

        // P = exp(S - m), row-sum into l
        float ls = 0.f;
#pragma unroll
        for (int r = 0; r < 16; r++) {
            float p0 = __expf(s0[r] - m_run);
            float p1 = __expf(s1[r] - m_run);
            s0[r] = p0; s1[r] = p1;
            ls += p0 + p1;
        }
        ls += __shfl_xor(ls, 32);
        l_run += ls;

        // P -> bf16 A-frags via pack + permlane32_swap; PV slices 0,1 (kv 0..31)
        {
            u32 c0 = pk2(s0[0], s0[1]),   c1 = pk2(s0[2], s0[3]),
                c2 = pk2(s0[4], s0[5]),   c3 = pk2(s0[6], s0[7]),
                c4 = pk2(s0[8], s0[9]),   c5 = pk2(s0[10], s0[11]),
                c6 = pk2(s0[12], s0[13]), c7 = pk2(s0[14], s0[15]);
            uint2v wA = __builtin_amdgcn_permlane32_swap(c0, c2, false, false);
            uint2v wB = __builtin_amdgcn_permlane32_swap(c1, c3, false, false);
            uint2v wC = __builtin_amdgcn_permlane32_swap(c4, c6, false, false);
            uint2v wD = __builtin_amdgcn_permlane32_swap(c5, c7, false, false);
            short8 paA = mk8(wA[0], wB[0], wA[1], wB[1]);
            short8 paB = mk8(wC[0], wD[0], wC[1], wD[1]);
#pragma unroll
            for (int sl = 0; sl < 2; sl++) {
                short8 pa = (sl == 0) ? paA : paB;
                int ch = ((sl * 2 + hi) ^ x7) * 8;
                short8 va = *(const short8*)&VLb[l31 * 64 + ch];
                o0 = __builtin_amdgcn_mfma_f32_32x32x16_bf16(pa, va, o0, 0, 0, 0);
                short8 vb2 = *(const short8*)&VLb[(32 + l31) * 64 + ch];
                o1 = __builtin_amdgcn_mfma_f32_32x32x16_bf16(pa, vb2, o1, 0, 0, 0);
            }
        }
        // PV slices 2,3 (kv 32..63)
        {
            u32 c0 = pk2(s1[0], s1[1]),   c1 = pk2(s1[2], s1[3]),
                c2 = pk2(s1[4], s1[5]),   c3 = pk2(s1[6], s1[7]),
                c4 = pk2(s1[8], s1[9]),   c5 = pk2(s1[10], s1[11]),
                c6 = pk2(s1[12], s1[13]), c7 = pk2(s1[14], s1[15]);
            uint2v wA = __builtin_amdgcn_permlane32_swap(c0, c2, false, false);
            uint2v wB = __builtin_amdgcn_permlane32_swap(c1, c3, false, false);
            uint2v wC = __builtin_amdgcn_permlane32_swap(c4, c6, false, false);
            uint2v wD = __builtin_amdgcn_permlane32_swap(c5, c7, false, false);
            short8 paC = mk8(wA[0], wB[0], wA[1], wB[1]);
            short8 paD = mk8(wC[0], wD[0], wC[1], wD[1]);
#pragma unroll
            for (int sl = 2; sl < 4; sl++) {
                short8 pa = (sl == 2) ? paC : paD;
                int ch = ((sl * 2 + hi) ^ x7) * 8;
                short8 va = *(const short8*)&VLb[l31 * 64 + ch];
                o0 = __builtin_amdgcn_mfma_f32_32x32x16_bf16(pa, va, o0, 0, 0, 0);
                short8 vb2 = *(const short8*)&VLb[(32 + l31) * 64 + ch];
                o1 = __builtin_amdgcn_mfma_f32_32x32x16_bf16(pa, vb2, o1, 0, 0, 0);
            }
        }
    }

    // epilogue: O / l, write bf16 to [B][T][C]
    const float inv = 1.0f / l_run;        // lane's own q = l31
    const int b = bh >> 4, h = bh & 15;
#pragma unroll
    for (int r = 0; r < 16; r++) {
        int qr = (r & 3) + 8 * (r >> 2) + 4 * hi;
        float invr = __shfl(inv, qr);
        int t = q0 + wid * 32 + qr;
        size_t rowoff = ((size_t)b * T_SEQ + t) * C_DIM + h * HD;
        O[rowoff + l31]      = f2bf(o0[r] * invr);
        O[rowoff + 32 + l31] = f2bf(o1[r] * invr);
    }
}

extern "C" void kernel_launch(void* const* d_in, const int* in_sizes, int n_in,
                              void* d_out, int out_size, void* d_ws, size_t ws_size,
                              hipStream_t stream) {
    const float* x     = (const float*)d_in[0];
    // d_in[1] = mask (causal, analytic — unused)
    const float* W_qkv = (const float*)d_in[2];
    const float* b_qkv = (const float*)d_in[3];
    const float* W_out = (const float*)d_in[4];
    const float* b_out = (const float*)d_in[5];
    float* out = (float*)d_out;

    char* w = (char*)d_ws;
    u16* xb    = (u16*)(w);                 // 16 MB: x-bf16, then reused as V^T
    u16* wqkvb = (u16*)(w + 16777216);
    u16* woutb = (u16*)(w + 23068672);
    u16* qb    = (u16*)(w + 25165824);
    u16* kb    = (u16*)(w + 41943040);
    u16* vb    = (u16*)(w + 58720256);      // V, then reused as attn output
    u16* vtb   = xb;                        // V^T [bh][d][t]
    u16* attnb = vb;                        // attn out [B][T][C]

    cvt_f32_bf16<<<4096, 256, 0, stream>>>(x, xb, 1048576);
    cvt_f32_bf16<<<1536, 256, 0, stream>>>(W_qkv, wqkvb, 393216);
    cvt_f32_bf16<<<512, 256, 0, stream>>>(W_out, woutb, 131072);

    gemm_bt<0><<<dim3(24, 64), 256, 0, stream>>>(xb, wqkvb, b_qkv, qb, kb, vb, nullptr,
                                                 8192, 3072, 1024);

    vtrans<<<dim3(16, 64), 256, 0, stream>>>(vb, vtb);

    attn_fwd2<<<1024, 256, 0, stream>>>(qb, kb, vtb, attnb);

    gemm_bt<1><<<dim3(8, 64), 256, 0, stream>>>(attnb, woutb, b_out, nullptr, nullptr,
                                                nullptr, out, 8192, 1024, 1024);
}

// Round 3
// 208.924 us; speedup vs baseline: 1.9346x; 1.3158x over previous
//
#include <hip/hip_runtime.h>
#include <hip/hip_bf16.h>

typedef unsigned short u16;
typedef unsigned int u32;
using short8 = __attribute__((ext_vector_type(8))) short;
using f32x4  = __attribute__((ext_vector_type(4))) float;
using f32x16 = __attribute__((ext_vector_type(16))) float;
using uint2v = __attribute__((ext_vector_type(2))) u32;

#define T_SEQ 2048
#define C_DIM 1024
#define NH 16
#define HD 64

#if __has_builtin(__builtin_amdgcn_exp2f)
#define EXP2(x) __builtin_amdgcn_exp2f(x)
#else
#define EXP2(x) exp2f(x)
#endif

__device__ __forceinline__ u16 f2bf(float f) {
    unsigned int u = __float_as_uint(f);
    unsigned int r = (u + 0x7fffu + ((u >> 16) & 1u)) >> 16;
    return (u16)r;
}
// hardware packed f32x2 -> bf16x2 (RNE), one VALU op
__device__ __forceinline__ u32 cvtpk(float lo, float hi) {
    u32 r;
    asm("v_cvt_pk_bf16_f32 %0, %1, %2" : "=v"(r) : "v"(lo), "v"(hi));
    return r;
}
__device__ __forceinline__ short8 mk8(u32 a, u32 b, u32 c, u32 d) {
    union { u32 u[4]; short8 s; } t;
    t.u[0] = a; t.u[1] = b; t.u[2] = c; t.u[3] = d;
    return t.s;
}
// global -> LDS direct DMA, 16B per lane; LDS dest = wave-uniform base + lane*16
__device__ __forceinline__ void gl_lds16(const u16* g, u16* l) {
    __builtin_amdgcn_global_load_lds(
        (const __attribute__((address_space(1))) unsigned int*)g,
        (__attribute__((address_space(3))) unsigned int*)l, 16, 0, 0);
}

// ---------------- fp32 -> bf16 convert, 8 elems/thread ----------------
__global__ __launch_bounds__(256) void cvt_f32_bf16(const float* __restrict__ in,
                                                    u16* __restrict__ out, int n8) {
    int i = blockIdx.x * blockDim.x + threadIdx.x;
    if (i >= n8) return;
    const float4* p = (const float4*)in + (size_t)i * 2;
    float4 a = p[0], b = p[1];
    short8 o;
    o[0] = (short)f2bf(a.x); o[1] = (short)f2bf(a.y);
    o[2] = (short)f2bf(a.z); o[3] = (short)f2bf(a.w);
    o[4] = (short)f2bf(b.x); o[5] = (short)f2bf(b.y);
    o[6] = (short)f2bf(b.z); o[7] = (short)f2bf(b.w);
    *(short8*)(out + (size_t)i * 8) = o;
}

// ---------------- bf16 GEMM (m97 structure): C = A * Bt^T + bias ----------------
// 128x128 tile, BK=32, 256 thr (4 waves, 2x2 of 64x64), global_load_lds staging.
// EPI=0: scatter to Q/K/V bf16 [BH][T][D] (+bias, Q pre-scaled by 0.125*log2e).
// EPI=1: fp32 C with bias.
template <int EPI>
__global__ __launch_bounds__(256) void gemm_bt(const u16* __restrict__ A,
                                               const u16* __restrict__ Bt,
                                               const float* __restrict__ bias,
                                               u16* __restrict__ qb, u16* __restrict__ kb,
                                               u16* __restrict__ vb, float* __restrict__ Cf,
                                               int M, int N, int K) {
    __shared__ __align__(16) u16 Al[128][32];
    __shared__ __align__(16) u16 Bl[128][32];
    const int tid = threadIdx.x;
    const int lane = tid & 63, wid = tid >> 6;
    const int li = lane & 15, g = lane >> 4;
    const int wr = (wid >> 1) * 64, wc = (wid & 1) * 64;
    const size_t m0 = (size_t)blockIdx.y * 128, n0 = (size_t)blockIdx.x * 128;

    // staging: wave w covers rows [w*32, w*32+32) via 2 issues of 16 rows;
    // 4 lanes per row, 16B each (row = lane>>2, col = (lane&3)*8 u16)
    const u16* aA = A + (m0 + wid * 32 + (lane >> 2)) * (size_t)K + (lane & 3) * 8;
    const u16* aB = Bt + (n0 + wid * 32 + (lane >> 2)) * (size_t)K + (lane & 3) * 8;
    u16* lA0 = &Al[wid * 32][0];
    u16* lA1 = &Al[wid * 32 + 16][0];
    u16* lB0 = &Bl[wid * 32][0];
    u16* lB1 = &Bl[wid * 32 + 16][0];

    f32x4 acc[4][4] = {};

    for (int k0 = 0; k0 < K; k0 += 32) {
        __syncthreads();                 // previous iteration's reads done
        gl_lds16(aA + k0, lA0);
        gl_lds16(aA + 16 * (size_t)K + k0, lA1);
        gl_lds16(aB + k0, lB0);
        gl_lds16(aB + 16 * (size_t)K + k0, lB1);
        __syncthreads();                 // drains vmcnt -> tile resident
        short8 af[4], bf[4];
#pragma unroll
        for (int i = 0; i < 4; i++) af[i] = *(const short8*)&Al[wr + i * 16 + li][g * 8];
#pragma unroll
        for (int i = 0; i < 4; i++) bf[i] = *(const short8*)&Bl[wc + i * 16 + li][g * 8];
#pragma unroll
        for (int mi = 0; mi < 4; mi++)
#pragma unroll
            for (int ni = 0; ni < 4; ni++)
                acc[mi][ni] = __builtin_amdgcn_mfma_f32_16x16x32_bf16(af[mi], bf[ni],
                                                                      acc[mi][ni], 0, 0, 0);
    }

#pragma unroll
    for (int mi = 0; mi < 4; mi++)
#pragma unroll
        for (int ni = 0; ni < 4; ni++)
#pragma unroll
            for (int r = 0; r < 4; r++) {
                size_t row = m0 + wr + mi * 16 + g * 4 + r;
                size_t col = n0 + wc + ni * 16 + li;
                float val = acc[mi][ni][r] + bias[col];
                if (EPI == 0) {
                    int which = (int)(col >> 10);
                    int rem = (int)(col & 1023);
                    int h = rem >> 6, d = rem & 63;
                    size_t b = row >> 11, t = row & 2047;
                    if (which == 0) val *= 0.18033688f;   // (1/8)*log2(e): exp2-domain
                    u16* dst = (which == 0) ? qb : (which == 1) ? kb : vb;
                    dst[(((b * NH) + h) * T_SEQ + t) * HD + d] = f2bf(val);
                } else {
                    Cf[row * (size_t)N + col] = val;
                }
            }
}

// ---------------- V transpose: [bh][t][d] -> [bh][d][t] ----------------
__global__ __launch_bounds__(256) void vtrans(const u16* __restrict__ V,
                                              u16* __restrict__ Vt) {
    __shared__ u16 L[128][72];
    const int tid = threadIdx.x;
    const int bh = blockIdx.y;
    const int t0 = blockIdx.x * 128;
    {
        int r = tid >> 1, cb = (tid & 1) * 32;
        const u16* src = V + ((size_t)bh * T_SEQ + t0 + r) * HD + cb;
#pragma unroll
        for (int j = 0; j < 4; j++)
            *(short8*)&L[r][cb + j * 8] = *(const short8*)(src + j * 8);
    }
    __syncthreads();
    {
        int d = tid >> 2, ts = (tid & 3) * 32;
        u16* dst = Vt + ((size_t)bh * HD + d) * T_SEQ + t0 + ts;
#pragma unroll
        for (int c = 0; c < 4; c++) {
            short8 o;
#pragma unroll
            for (int j = 0; j < 8; j++) o[j] = (short)L[ts + c * 8 + j][d];
            *(short8*)(dst + c * 8) = o;
        }
    }
}

// ---------------- causal flash attention, swapped-QK 32x32 MFMA ----------------
// 512 blocks, each handles the q-tile PAIR (15-p, p) sequentially -> exactly
// 34 KV-tile-units per block (dispatch-order-immune balance). 256 thr = 4 waves
// x 32 q-rows. K/Vt staged via global_load_lds, XOR-swizzled source, dbuf.
__global__ __launch_bounds__(256) void attn_fwd2(const u16* __restrict__ Q,
                                                 const u16* __restrict__ K,
                                                 const u16* __restrict__ Vt,
                                                 u16* __restrict__ O) {
    __shared__ __align__(16) u16 KL[2][64 * 64];
    __shared__ __align__(16) u16 VL[2][64 * 64];
    const int tid = threadIdx.x;
    const int lane = tid & 63, wid = tid >> 6;
    const int l31 = lane & 31, hi = lane >> 5;

    const int wg = blockIdx.x;
    const int xcd = wg & 7, idx = wg >> 3;       // idx 0..63
    const int bh = (xcd << 3) | (idx >> 3);      // 8 bh per XCD -> K/V L2-resident
    const int pair = idx & 7;
    const size_t bhT = (size_t)bh * T_SEQ;
    const int srow8 = lane >> 3, sch = lane & 7;
    const int b = bh >> 4, h = bh & 15;
    const int x7 = l31 & 7;

    for (int seg = 0; seg < 2; ++seg) {
        const int qt = seg ? pair : (15 - pair);
        const int q0 = qt * 128;
        const int qw0 = q0 + wid * 32;
        const int nkt = 2 * qt + 2;

        short8 qf[4];
        {
            const u16* qp = Q + (bhT + qw0 + l31) * HD + hi * 8;
#pragma unroll
            for (int s = 0; s < 4; s++) qf[s] = *(const short8*)(qp + s * 16);
        }

        f32x16 o0 = {}, o1 = {};
        float m_run = -3e38f, l_run = 0.f;

        // prologue: stage tile 0 into buffer 0 (prev segment's tail reads buf1)
#pragma unroll
        for (int i = 0; i < 2; i++) {
            int row = wid * 16 + i * 8 + srow8;
            int ch = sch ^ (row & 7);
            gl_lds16(K + (bhT + row) * HD + ch * 8, &KL[0][(wid * 16 + i * 8) * 64]);
            gl_lds16(Vt + ((size_t)bh * HD + row) * T_SEQ + ch * 8,
                     &VL[0][(wid * 16 + i * 8) * 64]);
        }

        for (int kt = 0; kt < nkt; kt++) {
            __syncthreads();   // drains vmcnt: tile kt resident; prev compute done
            if (kt + 1 < nkt) {
                const int kv0n = (kt + 1) * 64;
                const int nb = (kt + 1) & 1;
#pragma unroll
                for (int i = 0; i < 2; i++) {
                    int row = wid * 16 + i * 8 + srow8;
                    int ch = sch ^ (row & 7);
                    gl_lds16(K + (bhT + kv0n + row) * HD + ch * 8,
                             &KL[nb][(wid * 16 + i * 8) * 64]);
                    gl_lds16(Vt + ((size_t)bh * HD + row) * T_SEQ + kv0n + ch * 8,
                             &VL[nb][(wid * 16 + i * 8) * 64]);
                }
            }
            const int kv0 = kt * 64;
            if (kv0 > qw0) continue;     // wave-uniform; barriers stay at loop top
            const u16* KLb = KL[kt & 1];
            const u16* VLb = VL[kt & 1];

            // S^T[kv][q] = K . Q^T  (two kv-halves of 32); Q carries 0.125*log2e
            f32x16 s0 = {}, s1 = {};
            __builtin_amdgcn_s_setprio(1);
#pragma unroll
            for (int sl = 0; sl < 4; sl++) {
                int ch = ((sl * 2 + hi) ^ x7) * 8;
                short8 ka = *(const short8*)&KLb[l31 * 64 + ch];
                s0 = __builtin_amdgcn_mfma_f32_32x32x16_bf16(ka, qf[sl], s0, 0, 0, 0);
                short8 kb2 = *(const short8*)&KLb[(32 + l31) * 64 + ch];
                s1 = __builtin_amdgcn_mfma_f32_32x32x16_bf16(kb2, qf[sl], s1, 0, 0, 0);
            }
            __builtin_amdgcn_s_setprio(0);

            const int qg = qw0 + l31;
            if (kv0 + 63 > qw0) {       // boundary tile: causal mask
#pragma unroll
                for (int r = 0; r < 16; r++) {
                    int kvr = kv0 + (r & 3) + 8 * (r >> 2) + 4 * hi;
                    if (kvr > qg) s0[r] = -1e30f;
                    if (kvr + 32 > qg) s1[r] = -1e30f;
                }
            }

            // per-q max (lane-local, max3-fusable) + partner exchange
            float pm = -3e38f;
#pragma unroll
            for (int r = 0; r < 16; r++) pm = fmaxf(fmaxf(s0[r], s1[r]), pm);
            pm = fmaxf(pm, __shfl_xor(pm, 32));

            // defer-max (log2 domain): rescale only if some q grew by > 8 bits
            if (!__all(pm <= m_run + 8.0f)) {
                float mnew = fmaxf(m_run, pm);
                float alpha = EXP2(m_run - mnew);
                l_run *= alpha;
                m_run = mnew;
#pragma unroll
                for (int r = 0; r < 16; r++) {
                    int qr = (r & 3) + 8 * (r >> 2) + 4 * hi;
                    float ar = __shfl(alpha, qr);
                    o0[r] *= ar;
                    o1[r] *= ar;
                }
            }

            // P = 2^(S - m), row-sum into l
            float ls = 0.f;
#pragma unroll
            for (int r = 0; r < 16; r++) {
                float p0 = EXP2(s0[r] - m_run);
                float p1 = EXP2(s1[r] - m_run);
                s0[r] = p0; s1[r] = p1;
                ls += p0 + p1;
            }
            ls += __shfl_xor(ls, 32);
            l_run += ls;

            // P -> bf16 A-frags via cvt_pk + permlane32_swap; PV kv 0..31
            {
                u32 c0 = cvtpk(s0[0], s0[1]),   c1 = cvtpk(s0[2], s0[3]),
                    c2 = cvtpk(s0[4], s0[5]),   c3 = cvtpk(s0[6], s0[7]),
                    c4 = cvtpk(s0[8], s0[9]),   c5 = cvtpk(s0[10], s0[11]),
                    c6 = cvtpk(s0[12], s0[13]), c7 = cvtpk(s0[14], s0[15]);
                uint2v wA = __builtin_amdgcn_permlane32_swap(c0, c2, false, false);
                uint2v wB = __builtin_amdgcn_permlane32_swap(c1, c3, false, false);
                uint2v wC = __builtin_amdgcn_permlane32_swap(c4, c6, false, false);
                uint2v wD = __builtin_amdgcn_permlane32_swap(c5, c7, false, false);
                short8 paA = mk8(wA[0], wB[0], wA[1], wB[1]);
                short8 paB = mk8(wC[0], wD[0], wC[1], wD[1]);
                __builtin_amdgcn_s_setprio(1);
#pragma unroll
                for (int sl = 0; sl < 2; sl++) {
                    short8 pa = (sl == 0) ? paA : paB;
                    int ch = ((sl * 2 + hi) ^ x7) * 8;
                    short8 va = *(const short8*)&VLb[l31 * 64 + ch];
                    o0 = __builtin_amdgcn_mfma_f32_32x32x16_bf16(pa, va, o0, 0, 0, 0);
                    short8 vb2 = *(const short8*)&VLb[(32 + l31) * 64 + ch];
                    o1 = __builtin_amdgcn_mfma_f32_32x32x16_bf16(pa, vb2, o1, 0, 0, 0);
                }
                __builtin_amdgcn_s_setprio(0);
            }
            // PV kv 32..63
            {
                u32 c0 = cvtpk(s1[0], s1[1]),   c1 = cvtpk(s1[2], s1[3]),
                    c2 = cvtpk(s1[4], s1[5]),   c3 = cvtpk(s1[6], s1[7]),
                    c4 = cvtpk(s1[8], s1[9]),   c5 = cvtpk(s1[10], s1[11]),
                    c6 = cvtpk(s1[12], s1[13]), c7 = cvtpk(s1[14], s1[15]);
                uint2v wA = __builtin_amdgcn_permlane32_swap(c0, c2, false, false);
                uint2v wB = __builtin_amdgcn_permlane32_swap(c1, c3, false, false);
                uint2v wC = __builtin_amdgcn_permlane32_swap(c4, c6, false, false);
                uint2v wD = __builtin_amdgcn_permlane32_swap(c5, c7, false, false);
                short8 paC = mk8(wA[0], wB[0], wA[1], wB[1]);
                short8 paD = mk8(wC[0], wD[0], wC[1], wD[1]);
                __builtin_amdgcn_s_setprio(1);
#pragma unroll
                for (int sl = 2; sl < 4; sl++) {
                    short8 pa = (sl == 2) ? paC : paD;
                    int ch = ((sl * 2 + hi) ^ x7) * 8;
                    short8 va = *(const short8*)&VLb[l31 * 64 + ch];
                    o0 = __builtin_amdgcn_mfma_f32_32x32x16_bf16(pa, va, o0, 0, 0, 0);
                    short8 vb2 = *(const short8*)&VLb[(32 + l31) * 64 + ch];
                    o1 = __builtin_amdgcn_mfma_f32_32x32x16_bf16(pa, vb2, o1, 0, 0, 0);
                }
                __builtin_amdgcn_s_setprio(0);
            }
        }

        // epilogue: O / l, write bf16 to [B][T][C]
        const float inv = 1.0f / l_run;       // lane's own q-row = l31
#pragma unroll
        for (int r = 0; r < 16; r++) {
            int qr = (r & 3) + 8 * (r >> 2) + 4 * hi;
            float invr = __shfl(inv, qr);
            int t = q0 + wid * 32 + qr;
            size_t rowoff = ((size_t)b * T_SEQ + t) * C_DIM + h * HD;
            O[rowoff + l31]      = f2bf(o0[r] * invr);
            O[rowoff + 32 + l31] = f2bf(o1[r] * invr);
        }
    }
}

extern "C" void kernel_launch(void* const* d_in, const int* in_sizes, int n_in,
                              void* d_out, int out_size, void* d_ws, size_t ws_size,
                              hipStream_t stream) {
    const float* x     = (const float*)d_in[0];
    // d_in[1] = mask (causal, analytic — unused)
    const float* W_qkv = (const float*)d_in[2];
    const float* b_qkv = (const float*)d_in[3];
    const float* W_out = (const float*)d_in[4];
    const float* b_out = (const float*)d_in[5];
    float* out = (float*)d_out;

    char* w = (char*)d_ws;
    u16* xb    = (u16*)(w);                 // 16 MB: x-bf16, then reused as V^T
    u16* wqkvb = (u16*)(w + 16777216);
    u16* woutb = (u16*)(w + 23068672);
    u16* qb    = (u16*)(w + 25165824);
    u16* kb    = (u16*)(w + 41943040);
    u16* vb    = (u16*)(w + 58720256);      // V, then reused as attn output
    u16* vtb   = xb;                        // V^T [bh][d][t]
    u16* attnb = vb;                        // attn out [B][T][C]

    cvt_f32_bf16<<<4096, 256, 0, stream>>>(x, xb, 1048576);
    cvt_f32_bf16<<<1536, 256, 0, stream>>>(W_qkv, wqkvb, 393216);
    cvt_f32_bf16<<<512, 256, 0, stream>>>(W_out, woutb, 131072);

    gemm_bt<0><<<dim3(24, 64), 256, 0, stream>>>(xb, wqkvb, b_qkv, qb, kb, vb, nullptr,
                                                 8192, 3072, 1024);

    vtrans<<<dim3(16, 64), 256, 0, stream>>>(vb, vtb);

    attn_fwd2<<<512, 256, 0, stream>>>(qb, kb, vtb, attnb);

    gemm_bt<1><<<dim3(8, 64), 256, 0, stream>>>(attnb, woutb, b_out, nullptr, nullptr,
                                                nullptr, out, 8192, 1024, 1024);
}

// Round 4
// 201.646 us; speedup vs baseline: 2.0044x; 1.0361x over previous
//
#include <hip/hip_runtime.h>
#include <hip/hip_bf16.h>

typedef unsigned short u16;
typedef unsigned int u32;
using short8 = __attribute__((ext_vector_type(8))) short;
using f32x4  = __attribute__((ext_vector_type(4))) float;
using f32x16 = __attribute__((ext_vector_type(16))) float;
using uint2v = __attribute__((ext_vector_type(2))) u32;

#define T_SEQ 2048
#define C_DIM 1024
#define NH 16
#define HD 64

#if __has_builtin(__builtin_amdgcn_exp2f)
#define EXP2(x) __builtin_amdgcn_exp2f(x)
#else
#define EXP2(x) exp2f(x)
#endif

__device__ __forceinline__ u16 f2bf(float f) {
    unsigned int u = __float_as_uint(f);
    unsigned int r = (u + 0x7fffu + ((u >> 16) & 1u)) >> 16;
    return (u16)r;
}
// hardware packed f32x2 -> bf16x2 (RNE), one VALU op
__device__ __forceinline__ u32 cvtpk(float lo, float hi) {
    u32 r;
    asm("v_cvt_pk_bf16_f32 %0, %1, %2" : "=v"(r) : "v"(lo), "v"(hi));
    return r;
}
__device__ __forceinline__ short8 mk8(u32 a, u32 b, u32 c, u32 d) {
    union { u32 u[4]; short8 s; } t;
    t.u[0] = a; t.u[1] = b; t.u[2] = c; t.u[3] = d;
    return t.s;
}
// global -> LDS direct DMA, 16B per lane; LDS dest = wave-uniform base + lane*16
__device__ __forceinline__ void gl_lds16(const u16* g, u16* l) {
    __builtin_amdgcn_global_load_lds(
        (const __attribute__((address_space(1))) unsigned int*)g,
        (__attribute__((address_space(3))) unsigned int*)l, 16, 0, 0);
}
template <int N> __device__ __forceinline__ void s_vmcnt();
template <> __device__ __forceinline__ void s_vmcnt<0>() {
    asm volatile("s_waitcnt vmcnt(0)" ::: "memory");
}
template <> __device__ __forceinline__ void s_vmcnt<6>() {
    asm volatile("s_waitcnt vmcnt(6)" ::: "memory");
}
template <> __device__ __forceinline__ void s_vmcnt<7>() {
    asm volatile("s_waitcnt vmcnt(7)" ::: "memory");
}

// ---------------- fp32 -> bf16 convert, 8 elems/thread ----------------
__global__ __launch_bounds__(256) void cvt_f32_bf16(const float* __restrict__ in,
                                                    u16* __restrict__ out, int n8) {
    int i = blockIdx.x * blockDim.x + threadIdx.x;
    if (i >= n8) return;
    const float4* p = (const float4*)in + (size_t)i * 2;
    float4 a = p[0], b = p[1];
    short8 o;
    o[0] = (short)f2bf(a.x); o[1] = (short)f2bf(a.y);
    o[2] = (short)f2bf(a.z); o[3] = (short)f2bf(a.w);
    o[4] = (short)f2bf(b.x); o[5] = (short)f2bf(b.y);
    o[6] = (short)f2bf(b.z); o[7] = (short)f2bf(b.w);
    *(short8*)(out + (size_t)i * 8) = o;
}

// ------------- bf16 GEMM, counted-vmcnt pipelined (T2+T3+T4+T5) -------------
// BM=256, BN=64*NREP, BK=64, 512 thr = 8 waves (2M x 4N), per-wave 128 x 16*NREP.
// LDS XOR-swizzled (chunk ^= row&7) via pre-swizzled global source; raw s_barrier
// + s_waitcnt vmcnt(ISS): next tile's loads stay in flight across the barrier.
// EPI=0: scatter Q (x0.125*log2e), K to [BH][T][D]; V directly TRANSPOSED to
// [BH][D][T]. EPI=1: fp32 C + bias.
template <int EPI, int NREP, int NXT>
__global__ __launch_bounds__(512, 2) void gemm_big(const u16* __restrict__ A,
                                                   const u16* __restrict__ Bt,
                                                   const float* __restrict__ bias,
                                                   u16* __restrict__ qb,
                                                   u16* __restrict__ kb,
                                                   u16* __restrict__ vtb,
                                                   float* __restrict__ Cf, int N_) {
    constexpr int KD = 1024, NT = KD / 64, ISS = 4 + NREP, BN = 64 * NREP;
    __shared__ __align__(16) u16 AL[2][256 * 64];
    __shared__ __align__(16) u16 BL[2][BN * 64];
    const int tid = threadIdx.x;
    const int lane = tid & 63, wid = tid >> 6;
    const int li = lane & 15, g = lane >> 4;
    const int wm = wid >> 2, wn = wid & 3;
    const int r8 = lane >> 3, ch = (lane & 7) ^ r8;   // pre-swizzled source chunk

    const int b0 = blockIdx.x, nwg = gridDim.x;
    const int swz = (b0 & 7) * (nwg >> 3) + (b0 >> 3);  // XCD-chunked
    const int bx = swz % NXT, by = swz / NXT;
    const size_t m0 = (size_t)by * 256, n0 = (size_t)bx * BN;

    const u16* aBase = A + (m0 + wid * 8 + r8) * (size_t)KD + ch * 8;
    const u16* bBase = Bt + (n0 + wid * 8 + r8) * (size_t)KD + ch * 8;

    f32x4 acc[8][NREP] = {};

    auto STAGE = [&](int buf, int t) {
        const int k0 = t * 64;
#pragma unroll
        for (int i = 0; i < 4; i++)
            gl_lds16(aBase + (size_t)i * 64 * KD + k0, &AL[buf][(i * 64 + wid * 8) * 64]);
#pragma unroll
        for (int j = 0; j < NREP; j++)
            gl_lds16(bBase + (size_t)j * 64 * KD + k0, &BL[buf][(j * 64 + wid * 8) * 64]);
    };

    auto COMPUTE = [&](int buf) {
        const u16* Ab = &AL[buf][0];
        const u16* Bb = &BL[buf][0];
#pragma unroll
        for (int kk = 0; kk < 2; kk++) {
            short8 bf[NREP], af[8];
            const int x7 = li & 7;
#pragma unroll
            for (int ni = 0; ni < NREP; ni++) {
                int r = wn * (16 * NREP) + ni * 16 + li;
                int cc = ((kk * 4 + g) ^ x7) * 8;
                bf[ni] = *(const short8*)&Bb[r * 64 + cc];
            }
#pragma unroll
            for (int mi = 0; mi < 8; mi++) {
                int r = wm * 128 + mi * 16 + li;
                int cc = ((kk * 4 + g) ^ x7) * 8;
                af[mi] = *(const short8*)&Ab[r * 64 + cc];
            }
            __builtin_amdgcn_s_setprio(1);
#pragma unroll
            for (int mi = 0; mi < 8; mi++)
#pragma unroll
                for (int ni = 0; ni < NREP; ni++)
                    acc[mi][ni] = __builtin_amdgcn_mfma_f32_16x16x32_bf16(
                        af[mi], bf[ni], acc[mi][ni], 0, 0, 0);
            __builtin_amdgcn_s_setprio(0);
        }
    };

    STAGE(0, 0);
    STAGE(1, 1);            // 2*ISS loads in flight
#pragma unroll 1
    for (int t = 0; t < NT - 1; ++t) {
        s_vmcnt<ISS>();                    // tile t resident; tile t+1 still in flight
        __builtin_amdgcn_s_barrier();
        COMPUTE(t & 1);
        __builtin_amdgcn_s_barrier();      // all waves done reading buf[t&1]
        if (t + 2 < NT) STAGE(t & 1, t + 2);
    }
    s_vmcnt<0>();
    __builtin_amdgcn_s_barrier();
    COMPUTE((NT - 1) & 1);

#pragma unroll
    for (int mi = 0; mi < 8; mi++)
#pragma unroll
        for (int ni = 0; ni < NREP; ni++)
#pragma unroll
            for (int r = 0; r < 4; r++) {
                size_t row = m0 + wm * 128 + mi * 16 + g * 4 + r;
                size_t col = n0 + wn * 16 * NREP + ni * 16 + li;
                float val = acc[mi][ni][r] + bias[col];
                if (EPI == 0) {
                    int which = (int)(col >> 10);
                    int rem = (int)(col & 1023);
                    int h = rem >> 6, d = rem & 63;
                    size_t b = row >> 11, t = row & 2047;
                    if (which == 0) {
                        val *= 0.18033688f;     // (1/8)*log2(e): exp2-domain softmax
                        qb[(((b * NH) + h) * T_SEQ + t) * HD + d] = f2bf(val);
                    } else if (which == 1) {
                        kb[(((b * NH) + h) * T_SEQ + t) * HD + d] = f2bf(val);
                    } else {                    // V: write transposed [BH][D][T]
                        vtb[(((b * NH) + h) * HD + d) * T_SEQ + t] = f2bf(val);
                    }
                } else {
                    Cf[row * (size_t)N_ + col] = val;
                }
            }
}

// ---------------- causal flash attention, swapped-QK 32x32 MFMA ----------------
// 512 blocks, each handles the q-tile PAIR (15-p, p) sequentially -> exactly
// 34 KV-tile-units per block (dispatch-order-immune balance). 256 thr = 4 waves
// x 32 q-rows. K/Vt staged via global_load_lds, XOR-swizzled source, dbuf.
__global__ __launch_bounds__(256) void attn_fwd2(const u16* __restrict__ Q,
                                                 const u16* __restrict__ K,
                                                 const u16* __restrict__ Vt,
                                                 u16* __restrict__ O) {
    __shared__ __align__(16) u16 KL[2][64 * 64];
    __shared__ __align__(16) u16 VL[2][64 * 64];
    const int tid = threadIdx.x;
    const int lane = tid & 63, wid = tid >> 6;
    const int l31 = lane & 31, hi = lane >> 5;

    const int wg = blockIdx.x;
    const int xcd = wg & 7, idx = wg >> 3;       // idx 0..63
    const int bh = (xcd << 3) | (idx >> 3);      // 8 bh per XCD -> K/V L2-resident
    const int pair = idx & 7;
    const size_t bhT = (size_t)bh * T_SEQ;
    const int srow8 = lane >> 3, sch = lane & 7;
    const int b = bh >> 4, h = bh & 15;
    const int x7 = l31 & 7;

    for (int seg = 0; seg < 2; ++seg) {
        const int qt = seg ? pair : (15 - pair);
        const int q0 = qt * 128;
        const int qw0 = q0 + wid * 32;
        const int nkt = 2 * qt + 2;

        short8 qf[4];
        {
            const u16* qp = Q + (bhT + qw0 + l31) * HD + hi * 8;
#pragma unroll
            for (int s = 0; s < 4; s++) qf[s] = *(const short8*)(qp + s * 16);
        }

        f32x16 o0 = {}, o1 = {};
        float m_run = -3e38f, l_run = 0.f;

        // prologue: stage tile 0 into buffer 0
#pragma unroll
        for (int i = 0; i < 2; i++) {
            int row = wid * 16 + i * 8 + srow8;
            int ch = sch ^ (row & 7);
            gl_lds16(K + (bhT + row) * HD + ch * 8, &KL[0][(wid * 16 + i * 8) * 64]);
            gl_lds16(Vt + ((size_t)bh * HD + row) * T_SEQ + ch * 8,
                     &VL[0][(wid * 16 + i * 8) * 64]);
        }

        for (int kt = 0; kt < nkt; kt++) {
            __syncthreads();   // drains vmcnt: tile kt resident; prev compute done
            if (kt + 1 < nkt) {
                const int kv0n = (kt + 1) * 64;
                const int nb = (kt + 1) & 1;
#pragma unroll
                for (int i = 0; i < 2; i++) {
                    int row = wid * 16 + i * 8 + srow8;
                    int ch = sch ^ (row & 7);
                    gl_lds16(K + (bhT + kv0n + row) * HD + ch * 8,
                             &KL[nb][(wid * 16 + i * 8) * 64]);
                    gl_lds16(Vt + ((size_t)bh * HD + row) * T_SEQ + kv0n + ch * 8,
                             &VL[nb][(wid * 16 + i * 8) * 64]);
                }
            }
            const int kv0 = kt * 64;
            if (kv0 > qw0) continue;     // wave-uniform; barriers stay at loop top
            const u16* KLb = KL[kt & 1];
            const u16* VLb = VL[kt & 1];

            // S^T[kv][q] = K . Q^T  (two kv-halves of 32); Q carries 0.125*log2e
            f32x16 s0 = {}, s1 = {};
            __builtin_amdgcn_s_setprio(1);
#pragma unroll
            for (int sl = 0; sl < 4; sl++) {
                int ch = ((sl * 2 + hi) ^ x7) * 8;
                short8 ka = *(const short8*)&KLb[l31 * 64 + ch];
                s0 = __builtin_amdgcn_mfma_f32_32x32x16_bf16(ka, qf[sl], s0, 0, 0, 0);
                short8 kb2 = *(const short8*)&KLb[(32 + l31) * 64 + ch];
                s1 = __builtin_amdgcn_mfma_f32_32x32x16_bf16(kb2, qf[sl], s1, 0, 0, 0);
            }
            __builtin_amdgcn_s_setprio(0);

            const int qg = qw0 + l31;
            if (kv0 + 63 > qw0) {       // boundary tile: causal mask
#pragma unroll
                for (int r = 0; r < 16; r++) {
                    int kvr = kv0 + (r & 3) + 8 * (r >> 2) + 4 * hi;
                    if (kvr > qg) s0[r] = -1e30f;
                    if (kvr + 32 > qg) s1[r] = -1e30f;
                }
            }

            // per-q max (lane-local) + partner exchange
            float pm = -3e38f;
#pragma unroll
            for (int r = 0; r < 16; r++) pm = fmaxf(fmaxf(s0[r], s1[r]), pm);
            pm = fmaxf(pm, __shfl_xor(pm, 32));

            // defer-max (log2 domain): rescale only if some q grew by > 8 bits
            if (!__all(pm <= m_run + 8.0f)) {
                float mnew = fmaxf(m_run, pm);
                float alpha = EXP2(m_run - mnew);
                l_run *= alpha;
                m_run = mnew;
#pragma unroll
                for (int r = 0; r < 16; r++) {
                    int qr = (r & 3) + 8 * (r >> 2) + 4 * hi;
                    float ar = __shfl(alpha, qr);
                    o0[r] *= ar;
                    o1[r] *= ar;
                }
            }

            // P = 2^(S - m), row-sum into l
            float ls = 0.f;
#pragma unroll
            for (int r = 0; r < 16; r++) {
                float p0 = EXP2(s0[r] - m_run);
                float p1 = EXP2(s1[r] - m_run);
                s0[r] = p0; s1[r] = p1;
                ls += p0 + p1;
            }
            ls += __shfl_xor(ls, 32);
            l_run += ls;

            // P -> bf16 A-frags via cvt_pk + permlane32_swap; PV kv 0..31
            {
                u32 c0 = cvtpk(s0[0], s0[1]),   c1 = cvtpk(s0[2], s0[3]),
                    c2 = cvtpk(s0[4], s0[5]),   c3 = cvtpk(s0[6], s0[7]),
                    c4 = cvtpk(s0[8], s0[9]),   c5 = cvtpk(s0[10], s0[11]),
                    c6 = cvtpk(s0[12], s0[13]), c7 = cvtpk(s0[14], s0[15]);
                uint2v wA = __builtin_amdgcn_permlane32_swap(c0, c2, false, false);
                uint2v wB = __builtin_amdgcn_permlane32_swap(c1, c3, false, false);
                uint2v wC = __builtin_amdgcn_permlane32_swap(c4, c6, false, false);
                uint2v wD = __builtin_amdgcn_permlane32_swap(c5, c7, false, false);
                short8 paA = mk8(wA[0], wB[0], wA[1], wB[1]);
                short8 paB = mk8(wC[0], wD[0], wC[1], wD[1]);
                __builtin_amdgcn_s_setprio(1);
#pragma unroll
                for (int sl = 0; sl < 2; sl++) {
                    short8 pa = (sl == 0) ? paA : paB;
                    int ch = ((sl * 2 + hi) ^ x7) * 8;
                    short8 va = *(const short8*)&VLb[l31 * 64 + ch];
                    o0 = __builtin_amdgcn_mfma_f32_32x32x16_bf16(pa, va, o0, 0, 0, 0);
                    short8 vb2 = *(const short8*)&VLb[(32 + l31) * 64 + ch];
                    o1 = __builtin_amdgcn_mfma_f32_32x32x16_bf16(pa, vb2, o1, 0, 0, 0);
                }
                __builtin_amdgcn_s_setprio(0);
            }
            // PV kv 32..63
            {
                u32 c0 = cvtpk(s1[0], s1[1]),   c1 = cvtpk(s1[2], s1[3]),
                    c2 = cvtpk(s1[4], s1[5]),   c3 = cvtpk(s1[6], s1[7]),
                    c4 = cvtpk(s1[8], s1[9]),   c5 = cvtpk(s1[10], s1[11]),
                    c6 = cvtpk(s1[12], s1[13]), c7 = cvtpk(s1[14], s1[15]);
                uint2v wA = __builtin_amdgcn_permlane32_swap(c0, c2, false, false);
                uint2v wB = __builtin_amdgcn_permlane32_swap(c1, c3, false, false);
                uint2v wC = __builtin_amdgcn_permlane32_swap(c4, c6, false, false);
                uint2v wD = __builtin_amdgcn_permlane32_swap(c5, c7, false, false);
                short8 paC = mk8(wA[0], wB[0], wA[1], wB[1]);
                short8 paD = mk8(wC[0], wD[0], wC[1], wD[1]);
                __builtin_amdgcn_s_setprio(1);
#pragma unroll
                for (int sl = 2; sl < 4; sl++) {
                    short8 pa = (sl == 2) ? paC : paD;
                    int ch = ((sl * 2 + hi) ^ x7) * 8;
                    short8 va = *(const short8*)&VLb[l31 * 64 + ch];
                    o0 = __builtin_amdgcn_mfma_f32_32x32x16_bf16(pa, va, o0, 0, 0, 0);
                    short8 vb2 = *(const short8*)&VLb[(32 + l31) * 64 + ch];
                    o1 = __builtin_amdgcn_mfma_f32_32x32x16_bf16(pa, vb2, o1, 0, 0, 0);
                }
                __builtin_amdgcn_s_setprio(0);
            }
        }

        // epilogue: O / l, write bf16 to [B][T][C]
        const float inv = 1.0f / l_run;       // lane's own q-row = l31
#pragma unroll
        for (int r = 0; r < 16; r++) {
            int qr = (r & 3) + 8 * (r >> 2) + 4 * hi;
            float invr = __shfl(inv, qr);
            int t = q0 + wid * 32 + qr;
            size_t rowoff = ((size_t)b * T_SEQ + t) * C_DIM + h * HD;
            O[rowoff + l31]      = f2bf(o0[r] * invr);
            O[rowoff + 32 + l31] = f2bf(o1[r] * invr);
        }
    }
}

extern "C" void kernel_launch(void* const* d_in, const int* in_sizes, int n_in,
                              void* d_out, int out_size, void* d_ws, size_t ws_size,
                              hipStream_t stream) {
    const float* x     = (const float*)d_in[0];
    // d_in[1] = mask (causal, analytic — unused)
    const float* W_qkv = (const float*)d_in[2];
    const float* b_qkv = (const float*)d_in[3];
    const float* W_out = (const float*)d_in[4];
    const float* b_out = (const float*)d_in[5];
    float* out = (float*)d_out;

    char* w = (char*)d_ws;
    u16* xb    = (u16*)(w);                 // 16 MB: x-bf16; dead after QKV -> attn out
    u16* wqkvb = (u16*)(w + 16777216);
    u16* woutb = (u16*)(w + 23068672);
    u16* qb    = (u16*)(w + 25165824);
    u16* kb    = (u16*)(w + 41943040);
    u16* vtb   = (u16*)(w + 58720256);      // V^T [BH][D][T], written by QKV GEMM
    u16* attnb = xb;

    cvt_f32_bf16<<<4096, 256, 0, stream>>>(x, xb, 1048576);
    cvt_f32_bf16<<<1536, 256, 0, stream>>>(W_qkv, wqkvb, 393216);
    cvt_f32_bf16<<<512, 256, 0, stream>>>(W_out, woutb, 131072);

    // QKV: [8192x1024] x [3072x1024]^T; BN=192 -> 512 blocks = 2.0 rounds/CU
    gemm_big<0, 3, 16><<<512, 512, 0, stream>>>(xb, wqkvb, b_qkv, qb, kb, vtb,
                                                nullptr, 3072);

    attn_fwd2<<<512, 256, 0, stream>>>(qb, kb, vtb, attnb);

    // out-proj: [8192x1024] x [1024x1024]^T; BN=128 -> 256 blocks = 1.0 round/CU
    gemm_big<1, 2, 8><<<256, 512, 0, stream>>>(attnb, woutb, b_out, nullptr, nullptr,
                                               nullptr, out, 1024);
}